// Round 8
// baseline (237.963 us; speedup 1.0000x reference)
//
#include <hip/hip_runtime.h>
#include <stdint.h>

typedef uint16_t u16;
typedef uint32_t u32;
typedef __attribute__((ext_vector_type(4))) float f32x4;
typedef __attribute__((ext_vector_type(4))) unsigned short us4;
typedef __attribute__((ext_vector_type(8))) unsigned short us8;

#define NB   16
#define NN   512
#define FF   625      // H*W
#define FH   937      // int(625*1.5)
#define ROWS 8192     // NB*NN
#define KS1  1280     // [X(625) pad->640 | t1(625) pad->640]
#define KS2  1920     // [h(937) pad->960 | t2(937) pad->960]
#define NPX  640      // padded F   (t1 cols / Xt rows per batch)
#define NPH  960      // padded Fh  (t2 cols / ht rows per batch)
#define F4   160      // 640/4 f32x4 slots per padded X row
#define ITILE 8       // i-rows per build_L_tiled block

using frag_ab = __attribute__((ext_vector_type(8))) short;  // 8 bf16
using frag_cd = __attribute__((ext_vector_type(4))) float;  // 4 fp32

__device__ __forceinline__ u16 f32_bf16(float f) {
  union { float f; uint32_t u; } x; x.f = f;
  uint32_t r = x.u + 0x7fffu + ((x.u >> 16) & 1u);   // RNE
  return (u16)(r >> 16);
}
__device__ __forceinline__ void gload_lds16(const void* g, void* l) {
  __builtin_amdgcn_global_load_lds((__attribute__((address_space(1))) void*)g,
                                   (__attribute__((address_space(3))) void*)l,
                                   16, 0, 0);
}

// ---------------------------------------------------------------------------
// prep: fused pad_x + Xt + W1t + W2t + per-batch att bitonic sort.
//  [0,4096)       pad_x (XCD-aligned)
//  [4096,9216)    Xt transpose (XCD-aligned)
//  [9216,10496)   W1 -> W1t
//  [10496,11696)  W2 -> W2t
//  [11696,11712)  sort_att: per batch, sort (att, idx) -> att_s, ord_g
// ---------------------------------------------------------------------------
__global__ __launch_bounds__(256) void prep(
    const float* __restrict__ x4, const float* __restrict__ att,
    const float* __restrict__ W1, const float* __restrict__ W2,
    f32x4* __restrict__ Xpad, u16* __restrict__ Xcat, u16* __restrict__ Xt,
    u16* __restrict__ W1t, u16* __restrict__ W2t,
    float* __restrict__ att_s, u16* __restrict__ ord_g)
{
  const int blk = blockIdx.x;
  const int tid = threadIdx.x;
  if (blk < 4096) {
    const int xcd = blk & 7, loc = blk >> 3;      // loc 0..511
    const int row0 = xcd * 1024 + loc * 2;
    for (int s = tid; s < 320; s += 256) {
      const int row = row0 + (s >= 160);
      const int k4 = (s >= 160) ? s - 160 : s;
      f32x4 v; us4 o;
      #pragma unroll
      for (int t = 0; t < 4; ++t) {
        const int f = k4 * 4 + t;
        float x = (f < FF) ? x4[(size_t)row * FF + f] : 0.f;
        v[t] = x; o[t] = f32_bf16(x);
      }
      Xpad[(size_t)row * F4 + k4] = v;
      *(us4*)(Xcat + (size_t)row * KS1 + k4 * 4) = o;
    }
  } else if (blk < 9216) {
    __shared__ float tile[32][33];
    const int bb = blk - 4096;
    const int xcd = bb & 7, sub = bb >> 3;        // sub 0..639
    const int b = xcd * 2 + sub / 320;
    const int t = sub % 320;
    const int ft = t % 20, kt = t / 20;
    const int tx = tid & 31, ty = tid >> 5;
    #pragma unroll
    for (int r = 0; r < 4; ++r) {
      const int node = kt * 32 + ty + r * 8;
      const int f = ft * 32 + tx;
      tile[ty + r * 8][tx] = (f < FF) ? x4[((size_t)b * NN + node) * FF + f] : 0.f;
    }
    __syncthreads();
    #pragma unroll
    for (int r = 0; r < 4; ++r) {
      const int f = ft * 32 + ty + r * 8;
      const int node = kt * 32 + tx;
      Xt[((size_t)b * NPX + f) * 512 + node] = f32_bf16(tile[tx][ty + r * 8]);
    }
  } else if (blk < 10496) {
    __shared__ float tile[32][33];
    const int bb = blk - 9216;                    // 40 kt x 32 nt
    const int kt = bb % 40, nt = bb / 40;
    const int tx = tid & 31, ty = tid >> 5;
    #pragma unroll
    for (int r = 0; r < 4; ++r) {
      int k = kt * 32 + ty + r * 8;
      int n = nt * 32 + tx;
      float v = 0.f;
      int c = -1, kk = 0;
      if (k < 625) { c = 0; kk = k; }
      else if (k >= 640 && k < 1265) { c = 1; kk = k - 640; }
      if (c >= 0 && n < FH) v = W1[((size_t)c * 625 + kk) * FH + n];
      tile[ty + r * 8][tx] = v;
    }
    __syncthreads();
    #pragma unroll
    for (int r = 0; r < 4; ++r) {
      int n = nt * 32 + ty + r * 8;
      int k = kt * 32 + tx;
      W1t[(size_t)n * KS1 + k] = f32_bf16(tile[tx][ty + r * 8]);
    }
  } else if (blk < 11696) {
    __shared__ float tile[32][33];
    const int bb = blk - 10496;                   // 60 kt x 20 nt
    const int kt = bb % 60, nt = bb / 60;
    const int tx = tid & 31, ty = tid >> 5;
    #pragma unroll
    for (int r = 0; r < 4; ++r) {
      int k = kt * 32 + ty + r * 8;
      int n = nt * 32 + tx;
      float v = 0.f;
      int c = -1, kk = 0;
      if (k < 937) { c = 0; kk = k; }
      else if (k >= 960 && k < 1897) { c = 1; kk = k - 960; }
      if (c >= 0 && n < FF) v = W2[((size_t)c * 937 + kk) * FF + n];
      tile[ty + r * 8][tx] = v;
    }
    __syncthreads();
    #pragma unroll
    for (int r = 0; r < 4; ++r) {
      int n = nt * 32 + ty + r * 8;
      int k = kt * 32 + tx;
      W2t[(size_t)n * KS2 + k] = f32_bf16(tile[tx][ty + r * 8]);
    }
  } else {
    // bitonic sort of (att, idx) per batch
    __shared__ float sa[512];
    __shared__ u16 so[512];
    const int b = blk - 11696;
    sa[tid] = att[b * NN + tid]; sa[tid + 256] = att[b * NN + tid + 256];
    so[tid] = (u16)tid; so[tid + 256] = (u16)(tid + 256);
    for (int k = 2; k <= 512; k <<= 1) {
      for (int j = k >> 1; j > 0; j >>= 1) {
        __syncthreads();
        const int i = ((tid & ~(j - 1)) << 1) | (tid & (j - 1));
        const int p = i | j;
        const bool up = ((i & k) == 0);
        const float va = sa[i], vp = sa[p];
        if ((va > vp) == up) {
          sa[i] = vp; sa[p] = va;
          const u16 t = so[i]; so[i] = so[p]; so[p] = t;
        }
      }
    }
    __syncthreads();
    att_s[b * NN + tid] = sa[tid]; att_s[b * NN + tid + 256] = sa[tid + 256];
    ord_g[b * NN + tid] = so[tid]; ord_g[b * NN + tid + 256] = so[tid + 256];
  }
}

// ---------------------------------------------------------------------------
// build_L_tiled: block = 8 consecutive att-sorted i-rows of one batch.
// Xi tile in LDS (loaded once); candidate j's of the union window streamed,
// each j loaded once per 8 i's (8x less L2 than R7's one-row-per-block).
// Exact per-pair att/self checks; D math bitwise-identical to R7 build_L.
// L written in ORIGINAL coords: scatter of accepted entries over memset-0 L.
// ---------------------------------------------------------------------------
__global__ __launch_bounds__(256) void build_L_tiled(
    const f32x4* __restrict__ Xpad,
    const float* __restrict__ att_s, const u16* __restrict__ ord_g,
    u16* __restrict__ L)
{
  __shared__ f32x4 Xi[ITILE][F4];   // 20 KB
  __shared__ float as_[512];        // 2 KB
  __shared__ u16 ord[512];          // 1 KB
  __shared__ u32 mask[ITILE][16];   // 512 B  (bit per sorted j)
  __shared__ int deg[ITILE];
  __shared__ int jlo_s, jhi_s;
  __shared__ u16 dvs[ITILE];

  const int tid = threadIdx.x;
  const int blk = blockIdx.x;                  // 1024 blocks, XCD = blk&7
  const int xcd = blk & 7, sub = blk >> 3;     // sub 0..127
  const int b = xcd * 2 + (sub >> 6);
  const int it = sub & 63;
  const int s0 = it * ITILE;
  const f32x4* Xb4 = Xpad + (size_t)b * NN * F4;

  as_[tid] = att_s[b * NN + tid]; as_[tid + 256] = att_s[b * NN + tid + 256];
  ord[tid] = ord_g[b * NN + tid]; ord[tid + 256] = ord_g[b * NN + tid + 256];
  if (tid < ITILE * 16) ((u32*)mask)[tid] = 0;
  if (tid < ITILE) deg[tid] = 0;
  __syncthreads();

  // Xi gather (rows via ord) + window bounds
  for (int s = tid; s < ITILE * F4; s += 256) {
    const int ii = s / F4, k4 = s - ii * F4;
    Xi[ii][k4] = Xb4[(size_t)ord[s0 + ii] * F4 + k4];
  }
  if (tid == 0) {
    const float lot = as_[s0] - 0.05f;
    int lo = 0, hi = 512;
    while (lo < hi) { int m = (lo + hi) >> 1; if (as_[m] < lot) lo = m + 1; else hi = m; }
    jlo_s = lo;
  } else if (tid == 1) {
    const float hit = as_[s0 + ITILE - 1] + 0.05f;
    int lo = 0, hi = 512;
    while (lo < hi) { int m = (lo + hi) >> 1; if (as_[m] <= hit) lo = m + 1; else hi = m; }
    jhi_s = lo;
  }
  __syncthreads();

  const int hl = tid & 31;          // half-lane (dims split as in R7)
  const int hw = tid >> 5;          // half-wave 0..7
  const int jlo = jlo_s, jhi = jhi_s;

  for (int sj = jlo + hw; sj < jhi; sj += 8) {
    const int oj = ord[sj];
    const f32x4* Xj = Xb4 + (size_t)oj * F4;
    const f32x4 xj0 = Xj[hl];
    const f32x4 xj1 = Xj[32 + hl];
    const f32x4 xj2 = Xj[64 + hl];
    const f32x4 xj3 = Xj[96 + hl];
    const f32x4 xj4 = Xj[128 + hl];
    const float aj = as_[sj];
    #pragma unroll 2
    for (int ii = 0; ii < ITILE; ++ii) {
      const int si = s0 + ii;
      if (si == sj || fabsf(aj - as_[si]) > 0.05f) continue;
      const f32x4 d0 = Xi[ii][hl] - xj0;
      const f32x4 d1 = Xi[ii][32 + hl] - xj1;
      const f32x4 d2 = Xi[ii][64 + hl] - xj2;
      const f32x4 d3 = Xi[ii][96 + hl] - xj3;
      const f32x4 d4 = Xi[ii][128 + hl] - xj4;
      float p = 0.f;
      #pragma unroll
      for (int t = 0; t < 4; ++t)
        p += fabsf(d0[t]) + fabsf(d1[t]) + fabsf(d2[t]) + fabsf(d3[t]) + fabsf(d4[t]);
      #pragma unroll
      for (int off = 16; off; off >>= 1) p += __shfl_xor(p, off, 64);  // half-wave
      if (hl == 0 && p <= 180.0f) {
        atomicOr(&mask[ii][sj >> 5], 1u << (sj & 31));
        atomicAdd(&deg[ii], 1);
      }
    }
  }
  __syncthreads();

  if (tid < ITILE) dvs[tid] = f32_bf16(1.0f / (float)(deg[tid] + 1));
  __syncthreads();

  if (tid < ITILE * 16) {
    const int ii = tid >> 4, w = tid & 15;
    const int oi = ord[s0 + ii];
    u16* Lrow = L + ((size_t)b * 512 + oi) * 512;
    const u16 dv = dvs[ii];
    u32 m = mask[ii][w];
    while (m) {
      const int bit = __ffs(m) - 1;
      m &= m - 1;
      Lrow[ord[w * 32 + bit]] = dv;
    }
    if (w == 0) Lrow[oi] = dv;      // self (A+I diagonal)
  }
}

// ---------------------------------------------------------------------------
// gemm_core: 128M x NTILE-N, BK=64, XOR chunk swizzle (R5-R7 proven).
// TSTORE: additionally write bf16 result transposed into tbuf[b][col][node]
// (fuses the old transpose_h into gemm1's epilogue).
// ---------------------------------------------------------------------------
template <int KS, int NTILE, int NREAL, int NSTORE, bool RELU, bool BIAS,
          bool OUT_BF16, bool TSTORE>
__device__ __forceinline__ void gemm_core(
    const u16* __restrict__ At, const u16* __restrict__ Btt,
    const float* __restrict__ bias, void* __restrict__ C,
    u16* __restrict__ tbuf, long crow0, int col0, int ldc)
{
  constexpr int NI = NTILE / 32;
  constexpr int BR = NTILE / 32;
  __shared__ __align__(16) u16 Ash[128 * 64];
  __shared__ __align__(16) u16 Bsh[NTILE * 64];

  const int tid  = threadIdx.x;
  const int lane = tid & 63;
  const int wave = tid >> 6;
  const int wm = wave & 1, wn = wave >> 1;
  const int q = lane >> 4, l16 = lane & 15;

  const u16* pa[4]; const u16* pb[BR];
  #pragma unroll
  for (int r = 0; r < 4; ++r) {
    const int ci = r * 256 + tid;
    const int row = ci >> 3, cpos = ci & 7;
    pa[r] = At + (size_t)row * KS + (cpos ^ (row & 7)) * 8;
  }
  #pragma unroll
  for (int r = 0; r < BR; ++r) {
    const int ci = r * 256 + tid;
    const int row = ci >> 3, cpos = ci & 7;
    pb[r] = Btt + (size_t)row * KS + (cpos ^ (row & 7)) * 8;
  }
  const int wbase = (tid & 192) * 8;

  const frag_ab* fA[4][2]; const frag_ab* fB[NI][2];
  #pragma unroll
  for (int mi = 0; mi < 4; ++mi) {
    const int row = wm * 64 + mi * 16 + l16;
    fA[mi][0] = (const frag_ab*)&Ash[row * 64 + ((q    ) ^ (l16 & 7)) * 8];
    fA[mi][1] = (const frag_ab*)&Ash[row * 64 + ((q + 4) ^ (l16 & 7)) * 8];
  }
  #pragma unroll
  for (int ni = 0; ni < NI; ++ni) {
    const int row = wn * (NTILE / 2) + ni * 16 + l16;
    fB[ni][0] = (const frag_ab*)&Bsh[row * 64 + ((q    ) ^ (l16 & 7)) * 8];
    fB[ni][1] = (const frag_ab*)&Bsh[row * 64 + ((q + 4) ^ (l16 & 7)) * 8];
  }

  frag_cd acc[4][NI] = {};

  constexpr int KT = KS / 64;
  for (int kt = 0; kt < KT; ++kt) {
    __syncthreads();
    #pragma unroll
    for (int r = 0; r < 4; ++r) { gload_lds16(pa[r], &Ash[r * 2048 + wbase]); pa[r] += 64; }
    #pragma unroll
    for (int r = 0; r < BR; ++r) { gload_lds16(pb[r], &Bsh[r * 2048 + wbase]); pb[r] += 64; }
    __syncthreads();

    #pragma unroll
    for (int kk = 0; kk < 2; ++kk) {
      frag_ab av[4], bv[NI];
      #pragma unroll
      for (int mi = 0; mi < 4; ++mi) av[mi] = *fA[mi][kk];
      #pragma unroll
      for (int ni = 0; ni < NI; ++ni) bv[ni] = *fB[ni][kk];
      #pragma unroll
      for (int mi = 0; mi < 4; ++mi)
        #pragma unroll
        for (int ni = 0; ni < NI; ++ni)
          acc[mi][ni] = __builtin_amdgcn_mfma_f32_16x16x32_bf16(
              av[mi], bv[ni], acc[mi][ni], 0, 0, 0);
    }
  }

  #pragma unroll
  for (int ni = 0; ni < NI; ++ni) {
    const int col = col0 + wn * (NTILE / 2) + ni * 16 + l16;
    if (col >= NSTORE) continue;
    const bool ok = (col < NREAL);
    float bvv = 0.f;
    if (BIAS) bvv = ok ? bias[col] : 0.f;
    #pragma unroll
    for (int mi = 0; mi < 4; ++mi) {
      #pragma unroll
      for (int r = 0; r < 4; ++r) {
        const long rowg = crow0 + wm * 64 + mi * 16 + q * 4 + r;
        float v = acc[mi][ni][r];
        if (BIAS) v += bvv;
        if (RELU) v = fmaxf(v, 0.f);
        if (!ok) v = 0.f;
        if (OUT_BF16) ((u16*)C)[rowg * (size_t)ldc + col] = f32_bf16(v);
        else          ((float*)C)[rowg * (size_t)ldc + col] = v;
        if (TSTORE) {
          // fused transpose: ht[b][col][node], b=rowg>>9, node=rowg&511
          tbuf[((size_t)(rowg >> 9) * NPH + col) * 512 + (rowg & 511)] = f32_bf16(v);
        }
      }
    }
  }
}

template <int KS, int NTILE, int NREAL, int NSTORE, bool RELU, bool BIAS,
          bool OUT_BF16, bool TSTORE>
__global__ __launch_bounds__(256) void gemm_dense(
    const u16* __restrict__ A, const u16* __restrict__ Bt,
    const float* __restrict__ bias, void* __restrict__ C,
    u16* __restrict__ tbuf, int ldc)
{
  const int x = blockIdx.x;
  const int mt = ((x & 7) << 3) | (x >> 3);      // XCD-aligned m-tile (R6)
  gemm_core<KS, NTILE, NREAL, NSTORE, RELU, BIAS, OUT_BF16, TSTORE>(
      A + (size_t)mt * 128 * KS, Bt + (size_t)blockIdx.y * NTILE * KS,
      bias, C, tbuf, (long)mt * 128, blockIdx.y * NTILE, ldc);
}

// batched spmm: t = L_b · B_b^T; batch b on XCD b/2 (L2-local).
template <int NP>
__global__ __launch_bounds__(256) void spmm(
    const u16* __restrict__ L, const u16* __restrict__ Bt,
    u16* __restrict__ C, int ldc)
{
  constexpr int TPB = 4 * (NP / 64);
  const int blk = blockIdx.x;
  const int xcd = blk & 7, sub = blk >> 3;
  const int b = xcd * 2 + sub / TPB;
  const int t = sub % TPB;
  const int mt = t & 3, nt = t >> 2;
  gemm_core<512, 64, NP, NP, false, false, true, false>(
      L + ((size_t)b * 512 + mt * 128) * 512,
      Bt + ((size_t)b * NP + nt * 64) * 512,
      nullptr, C, nullptr, (long)b * 512 + mt * 128, nt * 64, ldc);
}

// ---------------------------------------------------------------------------
extern "C" void kernel_launch(void* const* d_in, const int* in_sizes, int n_in,
                              void* d_out, int out_size, void* d_ws, size_t ws_size,
                              hipStream_t stream) {
  const float* x4  = (const float*)d_in[0];
  const float* att = (const float*)d_in[1];
  const float* W1  = (const float*)d_in[2];
  const float* b1  = (const float*)d_in[3];
  const float* W2  = (const float*)d_in[4];
  const float* b2  = (const float*)d_in[5];
  float* out = (float*)d_out;

  char* ws = (char*)d_ws;
  f32x4* Xpad = (f32x4*)ws;                                 // 20.97 MB
  u16* ht = (u16*)ws;       ws += (size_t)ROWS * F4 * 16;   // ht (15.7 MB) aliases
                                                            // Xpad (dead after build_L)
  u16* Xcat = (u16*)ws;  ws += (size_t)ROWS * KS1 * 2;      // 20.97 MB
  u16* hcat = (u16*)ws;  ws += (size_t)ROWS * KS2 * 2;      // 31.46 MB
  u16* W1t  = (u16*)ws;  ws += (size_t)1024 * KS1 * 2;      //  2.62 MB
  u16* W2t  = (u16*)ws;  ws += (size_t)640 * KS2 * 2;       //  2.46 MB
  u16* Lm   = (u16*)ws;  ws += (size_t)NB * 512 * 512 * 2;  //  8.39 MB
  u16* Xt   = (u16*)ws;  ws += (size_t)NB * NPX * 512 * 2;  // 10.49 MB
  float* att_s = (float*)ws; ws += (size_t)NB * NN * 4;     // 32 KB
  u16* ord_g   = (u16*)ws;   ws += (size_t)NB * NN * 2;     // 16 KB

  prep<<<dim3(11712), 256, 0, stream>>>(x4, att, W1, W2, Xpad, Xcat, Xt,
                                        W1t, W2t, att_s, ord_g);
  hipMemsetAsync(Lm, 0, (size_t)NB * 512 * 512 * 2, stream);
  build_L_tiled<<<dim3(1024), 256, 0, stream>>>(Xpad, att_s, ord_g, Lm);
  spmm<NPX><<<dim3(640), 256, 0, stream>>>(Lm, Xt, Xcat + NPX, KS1);
  gemm_dense<KS1, 128, FH, NPH, true, true, true, true>
      <<<dim3(64, 8), 256, 0, stream>>>(Xcat, W1t, b1, (void*)hcat, ht, KS2);
  spmm<NPH><<<dim3(960), 256, 0, stream>>>(Lm, ht, hcat + NPH, KS2);
  gemm_dense<KS2, 64, FF, FF, true, true, false, false>
      <<<dim3(64, 10), 256, 0, stream>>>(hcat, W2t, b2, (void*)out, nullptr, FF);
}

// Round 9
// 229.788 us; speedup vs baseline: 1.0356x; 1.0356x over previous
//
#include <hip/hip_runtime.h>
#include <stdint.h>

typedef uint16_t u16;
typedef uint32_t u32;
typedef __attribute__((ext_vector_type(4))) float f32x4;
typedef __attribute__((ext_vector_type(4))) unsigned short us4;

#define NB   16
#define NN   512
#define FF   625      // H*W
#define FH   937      // int(625*1.5)
#define ROWS 8192     // NB*NN
#define KS1  1280     // [X(625) pad->640 | t1(625) pad->640]
#define KS2  1920     // [h(937) pad->960 | t2(937) pad->960]
#define NPX  640      // padded F
#define NPH  960      // padded Fh
#define F4   160      // 640/4 f32x4 slots per padded X row
#define ITILE 4       // i-rows per build_L_tiled block

using frag_ab = __attribute__((ext_vector_type(8))) short;  // 8 bf16
using frag_cd = __attribute__((ext_vector_type(4))) float;  // 4 fp32

__device__ __forceinline__ u16 f32_bf16(float f) {
  union { float f; uint32_t u; } x; x.f = f;
  uint32_t r = x.u + 0x7fffu + ((x.u >> 16) & 1u);   // RNE
  return (u16)(r >> 16);
}
__device__ __forceinline__ void gload_lds16(const void* g, void* l) {
  __builtin_amdgcn_global_load_lds((__attribute__((address_space(1))) void*)g,
                                   (__attribute__((address_space(3))) void*)l,
                                   16, 0, 0);
}

// ---------------------------------------------------------------------------
// prep: fused (x4 read ONCE) Xt-transpose+pad_x, W1t, W2t, att sort.
//  [0,5120)      per 32x32 tile of (node,f): write Xt (transposed) AND
//                Xpad f32x4 + Xcat bf16 (row-major) from the same LDS tile
//  [5120,6400)   W1 -> W1t [1024][KS1]
//  [6400,7600)   W2 -> W2t [640][KS2]
//  [7600,7616)   per-batch bitonic sort of (att, idx) -> att_s, ord_g
// ---------------------------------------------------------------------------
__global__ __launch_bounds__(256) void prep(
    const float* __restrict__ x4, const float* __restrict__ att,
    const float* __restrict__ W1, const float* __restrict__ W2,
    f32x4* __restrict__ Xpad, u16* __restrict__ Xcat, u16* __restrict__ Xt,
    u16* __restrict__ W1t, u16* __restrict__ W2t,
    float* __restrict__ att_s, u16* __restrict__ ord_g)
{
  const int blk = blockIdx.x;
  const int tid = threadIdx.x;
  if (blk < 5120) {
    __shared__ float tile[32][33];
    const int xcd = blk & 7, sub = blk >> 3;      // sub 0..639
    const int b = xcd * 2 + sub / 320;            // XCD-aligned batch
    const int t = sub % 320;
    const int ft = t % 20, kt = t / 20;           // f-tile 0..19, node-tile 0..15
    const int tx = tid & 31, ty = tid >> 5;
    #pragma unroll
    for (int r = 0; r < 4; ++r) {
      const int node = kt * 32 + ty + r * 8;
      const int f = ft * 32 + tx;
      tile[ty + r * 8][tx] = (f < FF) ? x4[((size_t)b * NN + node) * FF + f] : 0.f;
    }
    __syncthreads();
    #pragma unroll
    for (int r = 0; r < 4; ++r) {                 // Xt (transposed) write
      const int f = ft * 32 + ty + r * 8;
      const int node = kt * 32 + tx;
      Xt[((size_t)b * NPX + f) * 512 + node] = f32_bf16(tile[tx][ty + r * 8]);
    }
    // pad_x from the same tile: 32 nodes x 8 f32x4 slots
    const int nd = tid >> 3, sl = tid & 7;
    const int row = b * NN + kt * 32 + nd;
    f32x4 v; us4 o;
    #pragma unroll
    for (int t2 = 0; t2 < 4; ++t2) {
      const float x = tile[nd][sl * 4 + t2];
      v[t2] = x; o[t2] = f32_bf16(x);
    }
    Xpad[(size_t)row * F4 + ft * 8 + sl] = v;
    *(us4*)(Xcat + (size_t)row * KS1 + ft * 32 + sl * 4) = o;
  } else if (blk < 6400) {
    __shared__ float tile[32][33];
    const int bb = blk - 5120;                    // 40 kt x 32 nt
    const int kt = bb % 40, nt = bb / 40;
    const int tx = tid & 31, ty = tid >> 5;
    #pragma unroll
    for (int r = 0; r < 4; ++r) {
      int k = kt * 32 + ty + r * 8;
      int n = nt * 32 + tx;
      float v = 0.f;
      int c = -1, kk = 0;
      if (k < 625) { c = 0; kk = k; }
      else if (k >= 640 && k < 1265) { c = 1; kk = k - 640; }
      if (c >= 0 && n < FH) v = W1[((size_t)c * 625 + kk) * FH + n];
      tile[ty + r * 8][tx] = v;
    }
    __syncthreads();
    #pragma unroll
    for (int r = 0; r < 4; ++r) {
      int n = nt * 32 + ty + r * 8;
      int k = kt * 32 + tx;
      W1t[(size_t)n * KS1 + k] = f32_bf16(tile[tx][ty + r * 8]);
    }
  } else if (blk < 7600) {
    __shared__ float tile[32][33];
    const int bb = blk - 6400;                    // 60 kt x 20 nt
    const int kt = bb % 60, nt = bb / 60;
    const int tx = tid & 31, ty = tid >> 5;
    #pragma unroll
    for (int r = 0; r < 4; ++r) {
      int k = kt * 32 + ty + r * 8;
      int n = nt * 32 + tx;
      float v = 0.f;
      int c = -1, kk = 0;
      if (k < 937) { c = 0; kk = k; }
      else if (k >= 960 && k < 1897) { c = 1; kk = k - 960; }
      if (c >= 0 && n < FF) v = W2[((size_t)c * 937 + kk) * FF + n];
      tile[ty + r * 8][tx] = v;
    }
    __syncthreads();
    #pragma unroll
    for (int r = 0; r < 4; ++r) {
      int n = nt * 32 + ty + r * 8;
      int k = kt * 32 + tx;
      W2t[(size_t)n * KS2 + k] = f32_bf16(tile[tx][ty + r * 8]);
    }
  } else {
    __shared__ float sa[512];
    __shared__ u16 so[512];
    const int b = blk - 7600;
    sa[tid] = att[b * NN + tid]; sa[tid + 256] = att[b * NN + tid + 256];
    so[tid] = (u16)tid; so[tid + 256] = (u16)(tid + 256);
    for (int k = 2; k <= 512; k <<= 1) {
      for (int j = k >> 1; j > 0; j >>= 1) {
        __syncthreads();
        const int i = ((tid & ~(j - 1)) << 1) | (tid & (j - 1));
        const int p = i | j;
        const bool up = ((i & k) == 0);
        const float va = sa[i], vp = sa[p];
        if ((va > vp) == up) {
          sa[i] = vp; sa[p] = va;
          const u16 t = so[i]; so[i] = so[p]; so[p] = t;
        }
      }
    }
    __syncthreads();
    att_s[b * NN + tid] = sa[tid]; att_s[b * NN + tid + 256] = sa[tid + 256];
    ord_g[b * NN + tid] = so[tid]; ord_g[b * NN + tid + 256] = so[tid + 256];
  }
}

// ---------------------------------------------------------------------------
// build_L_tiled v2: 4 att-sorted i-rows per block, 2048 blocks (8/CU, ~15 KB
// LDS -> occupancy back to grid limit; R8's ITILE=8/1024 blocks sat at 29%).
// One j-row in regs per half-wave; 4 distances vs LDS Xi; PACKED 4-wide
// butterfly (amortizes the 5-step serial shfl chain — affordable now since
// i-side is in LDS, unlike R3's register blowup). Unconditional distance
// compute; att/self exactness enforced at accept. Full-row L writes in
// original coords via LDS inverse permutation (no global memset needed).
// ---------------------------------------------------------------------------
__global__ __launch_bounds__(256) void build_L_tiled(
    const f32x4* __restrict__ Xpad,
    const float* __restrict__ att_s, const u16* __restrict__ ord_g,
    u16* __restrict__ L)
{
  __shared__ f32x4 Xi[ITILE][F4];   // 10 KB
  __shared__ float as_[512];        // 2 KB
  __shared__ u16 ord[512];          // 1 KB
  __shared__ u16 inv[512];          // 1 KB
  __shared__ u32 mask[ITILE][16];   // 256 B
  __shared__ int deg[ITILE];
  __shared__ int jlo_s, jhi_s;

  const int tid = threadIdx.x;
  const int blk = blockIdx.x;                  // 2048, XCD = blk&7
  const int xcd = blk & 7, sub = blk >> 3;     // sub 0..255
  const int b = xcd * 2 + (sub >> 7);
  const int it = sub & 127;
  const int s0 = it * ITILE;
  const f32x4* Xb4 = Xpad + (size_t)b * NN * F4;

  as_[tid] = att_s[b * NN + tid]; as_[tid + 256] = att_s[b * NN + tid + 256];
  const u16 o0 = ord_g[b * NN + tid], o1 = ord_g[b * NN + tid + 256];
  ord[tid] = o0; ord[tid + 256] = o1;
  inv[o0] = (u16)tid; inv[o1] = (u16)(tid + 256);
  if (tid < ITILE * 16) ((u32*)mask)[tid] = 0;
  if (tid < ITILE) deg[tid] = 0;
  __syncthreads();

  for (int s = tid; s < ITILE * F4; s += 256) {
    const int ii = s / F4, k4 = s - ii * F4;
    Xi[ii][k4] = Xb4[(size_t)ord[s0 + ii] * F4 + k4];
  }
  if (tid == 0) {
    const float lot = as_[s0] - 0.05f;
    int lo = 0, hi = 512;
    while (lo < hi) { int m = (lo + hi) >> 1; if (as_[m] < lot) lo = m + 1; else hi = m; }
    jlo_s = lo;
  } else if (tid == 1) {
    const float hit = as_[s0 + ITILE - 1] + 0.05f;
    int lo = 0, hi = 512;
    while (lo < hi) { int m = (lo + hi) >> 1; if (as_[m] <= hit) lo = m + 1; else hi = m; }
    jhi_s = lo;
  }
  __syncthreads();

  const int hl = tid & 31;
  const int hw = tid >> 5;
  const int jlo = jlo_s, jhi = jhi_s;

  for (int sj = jlo + hw; sj < jhi; sj += 8) {
    const f32x4* Xj = Xb4 + (size_t)ord[sj] * F4;
    const f32x4 xj0 = Xj[hl];
    const f32x4 xj1 = Xj[32 + hl];
    const f32x4 xj2 = Xj[64 + hl];
    const f32x4 xj3 = Xj[96 + hl];
    const f32x4 xj4 = Xj[128 + hl];
    const float aj = as_[sj];
    f32x4 pv;
    #pragma unroll
    for (int ii = 0; ii < ITILE; ++ii) {
      const f32x4 d0 = Xi[ii][hl] - xj0;
      const f32x4 d1 = Xi[ii][32 + hl] - xj1;
      const f32x4 d2 = Xi[ii][64 + hl] - xj2;
      const f32x4 d3 = Xi[ii][96 + hl] - xj3;
      const f32x4 d4 = Xi[ii][128 + hl] - xj4;
      float p = 0.f;
      #pragma unroll
      for (int t = 0; t < 4; ++t)
        p += fabsf(d0[t]) + fabsf(d1[t]) + fabsf(d2[t]) + fabsf(d3[t]) + fabsf(d4[t]);
      pv[ii] = p;
    }
    #pragma unroll
    for (int off = 16; off; off >>= 1) {          // packed half-wave butterfly
      f32x4 o;
      o[0] = __shfl_xor(pv[0], off, 64);
      o[1] = __shfl_xor(pv[1], off, 64);
      o[2] = __shfl_xor(pv[2], off, 64);
      o[3] = __shfl_xor(pv[3], off, 64);
      pv += o;
    }
    if (hl == 0) {
      #pragma unroll
      for (int ii = 0; ii < ITILE; ++ii) {
        const int si = s0 + ii;
        if (si != sj && fabsf(aj - as_[si]) <= 0.05f && pv[ii] <= 180.0f) {
          atomicOr(&mask[ii][sj >> 5], 1u << (sj & 31));
          atomicAdd(&deg[ii], 1);
        }
      }
    }
  }
  __syncthreads();

  // full-row coalesced writes, original coords (diagonal = self)
  #pragma unroll
  for (int ii = 0; ii < ITILE; ++ii) {
    const int oi = ord[s0 + ii];
    const u16 dv = f32_bf16(1.0f / (float)(deg[ii] + 1));
    u16* Lrow = L + ((size_t)b * 512 + oi) * 512;
    const int j0 = 2 * tid;
    const int sA = inv[j0], sB = inv[j0 + 1];
    const u32 fA = (j0 == oi)     | ((mask[ii][sA >> 5] >> (sA & 31)) & 1u);
    const u32 fB = (j0 + 1 == oi) | ((mask[ii][sB >> 5] >> (sB & 31)) & 1u);
    *(u32*)(Lrow + j0) = (fA ? (u32)dv : 0u) | ((fB ? (u32)dv : 0u) << 16);
  }
}

// ---------------------------------------------------------------------------
// gemm_core: 128M x NTILE-N, BK=64, XOR chunk swizzle (R5-R7 proven).
// ---------------------------------------------------------------------------
template <int KS, int NTILE, int NREAL, int NSTORE, bool RELU, bool BIAS, bool OUT_BF16>
__device__ __forceinline__ void gemm_core(
    const u16* __restrict__ At, const u16* __restrict__ Btt,
    const float* __restrict__ bias, void* __restrict__ C,
    long crow0, int col0, int ldc)
{
  constexpr int NI = NTILE / 32;
  constexpr int BR = NTILE / 32;
  __shared__ __align__(16) u16 Ash[128 * 64];
  __shared__ __align__(16) u16 Bsh[NTILE * 64];

  const int tid  = threadIdx.x;
  const int lane = tid & 63;
  const int wave = tid >> 6;
  const int wm = wave & 1, wn = wave >> 1;
  const int q = lane >> 4, l16 = lane & 15;

  const u16* pa[4]; const u16* pb[BR];
  #pragma unroll
  for (int r = 0; r < 4; ++r) {
    const int ci = r * 256 + tid;
    const int row = ci >> 3, cpos = ci & 7;
    pa[r] = At + (size_t)row * KS + (cpos ^ (row & 7)) * 8;
  }
  #pragma unroll
  for (int r = 0; r < BR; ++r) {
    const int ci = r * 256 + tid;
    const int row = ci >> 3, cpos = ci & 7;
    pb[r] = Btt + (size_t)row * KS + (cpos ^ (row & 7)) * 8;
  }
  const int wbase = (tid & 192) * 8;

  const frag_ab* fA[4][2]; const frag_ab* fB[NI][2];
  #pragma unroll
  for (int mi = 0; mi < 4; ++mi) {
    const int row = wm * 64 + mi * 16 + l16;
    fA[mi][0] = (const frag_ab*)&Ash[row * 64 + ((q    ) ^ (l16 & 7)) * 8];
    fA[mi][1] = (const frag_ab*)&Ash[row * 64 + ((q + 4) ^ (l16 & 7)) * 8];
  }
  #pragma unroll
  for (int ni = 0; ni < NI; ++ni) {
    const int row = wn * (NTILE / 2) + ni * 16 + l16;
    fB[ni][0] = (const frag_ab*)&Bsh[row * 64 + ((q    ) ^ (l16 & 7)) * 8];
    fB[ni][1] = (const frag_ab*)&Bsh[row * 64 + ((q + 4) ^ (l16 & 7)) * 8];
  }

  frag_cd acc[4][NI] = {};

  constexpr int KT = KS / 64;
  for (int kt = 0; kt < KT; ++kt) {
    __syncthreads();
    #pragma unroll
    for (int r = 0; r < 4; ++r) { gload_lds16(pa[r], &Ash[r * 2048 + wbase]); pa[r] += 64; }
    #pragma unroll
    for (int r = 0; r < BR; ++r) { gload_lds16(pb[r], &Bsh[r * 2048 + wbase]); pb[r] += 64; }
    __syncthreads();

    #pragma unroll
    for (int kk = 0; kk < 2; ++kk) {
      frag_ab av[4], bv[NI];
      #pragma unroll
      for (int mi = 0; mi < 4; ++mi) av[mi] = *fA[mi][kk];
      #pragma unroll
      for (int ni = 0; ni < NI; ++ni) bv[ni] = *fB[ni][kk];
      #pragma unroll
      for (int mi = 0; mi < 4; ++mi)
        #pragma unroll
        for (int ni = 0; ni < NI; ++ni)
          acc[mi][ni] = __builtin_amdgcn_mfma_f32_16x16x32_bf16(
              av[mi], bv[ni], acc[mi][ni], 0, 0, 0);
    }
  }

  #pragma unroll
  for (int ni = 0; ni < NI; ++ni) {
    const int col = col0 + wn * (NTILE / 2) + ni * 16 + l16;
    if (col >= NSTORE) continue;
    const bool ok = (col < NREAL);
    float bvv = 0.f;
    if (BIAS) bvv = ok ? bias[col] : 0.f;
    #pragma unroll
    for (int mi = 0; mi < 4; ++mi) {
      #pragma unroll
      for (int r = 0; r < 4; ++r) {
        const long rowg = crow0 + wm * 64 + mi * 16 + q * 4 + r;
        float v = acc[mi][ni][r];
        if (BIAS) v += bvv;
        if (RELU) v = fmaxf(v, 0.f);
        if (!ok) v = 0.f;
        if (OUT_BF16) ((u16*)C)[rowg * (size_t)ldc + col] = f32_bf16(v);
        else          ((float*)C)[rowg * (size_t)ldc + col] = v;
      }
    }
  }
}

template <int KS, int NTILE, int NREAL, int NSTORE, bool RELU, bool BIAS, bool OUT_BF16>
__global__ __launch_bounds__(256) void gemm_dense(
    const u16* __restrict__ A, const u16* __restrict__ Bt,
    const float* __restrict__ bias, void* __restrict__ C, int ldc)
{
  const int x = blockIdx.x;
  const int mt = ((x & 7) << 3) | (x >> 3);      // XCD-aligned m-tile (R6)
  gemm_core<KS, NTILE, NREAL, NSTORE, RELU, BIAS, OUT_BF16>(
      A + (size_t)mt * 128 * KS, Bt + (size_t)blockIdx.y * NTILE * KS,
      bias, C, (long)mt * 128, blockIdx.y * NTILE, ldc);
}

// batched spmm: t = L_b · B_b^T; batch b on XCD b/2 (L2-local).
template <int NP>
__global__ __launch_bounds__(256) void spmm(
    const u16* __restrict__ L, const u16* __restrict__ Bt,
    u16* __restrict__ C, int ldc)
{
  constexpr int TPB = 4 * (NP / 64);
  const int blk = blockIdx.x;
  const int xcd = blk & 7, sub = blk >> 3;
  const int b = xcd * 2 + sub / TPB;
  const int t = sub % TPB;
  const int mt = t & 3, nt = t >> 2;
  gemm_core<512, 64, NP, NP, false, false, true>(
      L + ((size_t)b * 512 + mt * 128) * 512,
      Bt + ((size_t)b * NP + nt * 64) * 512,
      nullptr, C, (long)b * 512 + mt * 128, nt * 64, ldc);
}

// ---------------------------------------------------------------------------
// transpose_h (R7-proven, coalesced): hcat h-half -> ht [b][960][512] bf16.
// ---------------------------------------------------------------------------
__global__ __launch_bounds__(256) void transpose_h(
    const u16* __restrict__ hcat, u16* __restrict__ ht)
{
  __shared__ u16 tile[32][34];
  const int blk = blockIdx.x;                   // 7680
  const int xcd = blk & 7, sub = blk >> 3;      // sub 0..959
  const int b = xcd * 2 + sub / 480;
  const int t = sub % 480;
  const int kt = t % 16, nt = t / 16;
  const int tid = threadIdx.x;
  const int tx = tid & 31, ty = tid >> 5;
  #pragma unroll
  for (int r = 0; r < 4; ++r) {
    const int node = kt * 32 + ty + r * 8;
    const int n = nt * 32 + tx;
    tile[ty + r * 8][tx] = hcat[((size_t)b * NN + node) * KS2 + n];
  }
  __syncthreads();
  #pragma unroll
  for (int r = 0; r < 4; ++r) {
    const int n = nt * 32 + ty + r * 8;
    const int node = kt * 32 + tx;
    ht[((size_t)b * NPH + n) * 512 + node] = tile[tx][ty + r * 8];
  }
}

// ---------------------------------------------------------------------------
extern "C" void kernel_launch(void* const* d_in, const int* in_sizes, int n_in,
                              void* d_out, int out_size, void* d_ws, size_t ws_size,
                              hipStream_t stream) {
  const float* x4  = (const float*)d_in[0];
  const float* att = (const float*)d_in[1];
  const float* W1  = (const float*)d_in[2];
  const float* b1  = (const float*)d_in[3];
  const float* W2  = (const float*)d_in[4];
  const float* b2  = (const float*)d_in[5];
  float* out = (float*)d_out;

  char* ws = (char*)d_ws;
  f32x4* Xpad = (f32x4*)ws;                                 // 20.97 MB
  u16* ht = (u16*)ws;       ws += (size_t)ROWS * F4 * 16;   // ht aliases Xpad
                                                            // (dead after build_L)
  u16* Xcat = (u16*)ws;  ws += (size_t)ROWS * KS1 * 2;      // 20.97 MB
  u16* hcat = (u16*)ws;  ws += (size_t)ROWS * KS2 * 2;      // 31.46 MB
  u16* W1t  = (u16*)ws;  ws += (size_t)1024 * KS1 * 2;      //  2.62 MB
  u16* W2t  = (u16*)ws;  ws += (size_t)640 * KS2 * 2;       //  2.46 MB
  u16* Lm   = (u16*)ws;  ws += (size_t)NB * 512 * 512 * 2;  //  8.39 MB
  u16* Xt   = (u16*)ws;  ws += (size_t)NB * NPX * 512 * 2;  // 10.49 MB
  float* att_s = (float*)ws; ws += (size_t)NB * NN * 4;     // 32 KB
  u16* ord_g   = (u16*)ws;   ws += (size_t)NB * NN * 2;     // 16 KB

  prep<<<dim3(7616), 256, 0, stream>>>(x4, att, W1, W2, Xpad, Xcat, Xt,
                                       W1t, W2t, att_s, ord_g);
  build_L_tiled<<<dim3(2048), 256, 0, stream>>>(Xpad, att_s, ord_g, Lm);
  spmm<NPX><<<dim3(640), 256, 0, stream>>>(Lm, Xt, Xcat + NPX, KS1);
  gemm_dense<KS1, 128, FH, NPH, true, true, true>
      <<<dim3(64, 8), 256, 0, stream>>>(Xcat, W1t, b1, (void*)hcat, KS2);
  transpose_h<<<dim3(7680), 256, 0, stream>>>(hcat, ht);
  spmm<NPH><<<dim3(960), 256, 0, stream>>>(Lm, ht, hcat + NPH, KS2);
  gemm_dense<KS2, 64, FF, FF, true, true, false>
      <<<dim3(64, 10), 256, 0, stream>>>(hcat, W2t, b2, (void*)out, FF);
}

// Round 10
// 222.931 us; speedup vs baseline: 1.0674x; 1.0308x over previous
//
#include <hip/hip_runtime.h>
#include <stdint.h>

typedef uint16_t u16;
typedef uint32_t u32;
typedef __attribute__((ext_vector_type(4))) float f32x4;
typedef __attribute__((ext_vector_type(4))) unsigned short us4;

#define NB   16
#define NN   512
#define FF   625      // H*W
#define FH   937      // int(625*1.5)
#define ROWS 8192     // NB*NN
#define KS1  1280     // [X(625) pad->640 | t1(625) pad->640]
#define KS2  1920     // [h(937) pad->960 | t2(937) pad->960]
#define NPX  640      // padded F
#define NPH  960      // padded Fh
#define F4   160      // 640/4 f32x4 slots per padded X row
#define ITILE 4       // i-rows per build_L block

using frag_ab = __attribute__((ext_vector_type(8))) short;  // 8 bf16
using frag_cd = __attribute__((ext_vector_type(4))) float;  // 4 fp32

__device__ __forceinline__ u16 f32_bf16(float f) {
  union { float f; uint32_t u; } x; x.f = f;
  uint32_t r = x.u + 0x7fffu + ((x.u >> 16) & 1u);   // RNE
  return (u16)(r >> 16);
}
__device__ __forceinline__ void gload_lds16(const void* g, void* l) {
  __builtin_amdgcn_global_load_lds((__attribute__((address_space(1))) void*)g,
                                   (__attribute__((address_space(3))) void*)l,
                                   16, 0, 0);
}

// ---------------------------------------------------------------------------
// prep: fused (x4 read once) Xt+pad_x, W1t, W2t, att sort + gmask zeroing.
// ---------------------------------------------------------------------------
__global__ __launch_bounds__(256) void prep(
    const float* __restrict__ x4, const float* __restrict__ att,
    const float* __restrict__ W1, const float* __restrict__ W2,
    f32x4* __restrict__ Xpad, u16* __restrict__ Xcat, u16* __restrict__ Xt,
    u16* __restrict__ W1t, u16* __restrict__ W2t,
    float* __restrict__ att_s, u16* __restrict__ ord_g, u32* __restrict__ gmask)
{
  const int blk = blockIdx.x;
  const int tid = threadIdx.x;
  if (blk < 5120) {
    __shared__ float tile[32][33];
    const int xcd = blk & 7, sub = blk >> 3;      // sub 0..639
    const int b = xcd * 2 + sub / 320;            // XCD-aligned batch
    const int t = sub % 320;
    const int ft = t % 20, kt = t / 20;
    const int tx = tid & 31, ty = tid >> 5;
    #pragma unroll
    for (int r = 0; r < 4; ++r) {
      const int node = kt * 32 + ty + r * 8;
      const int f = ft * 32 + tx;
      tile[ty + r * 8][tx] = (f < FF) ? x4[((size_t)b * NN + node) * FF + f] : 0.f;
    }
    __syncthreads();
    #pragma unroll
    for (int r = 0; r < 4; ++r) {                 // Xt (transposed) write
      const int f = ft * 32 + ty + r * 8;
      const int node = kt * 32 + tx;
      Xt[((size_t)b * NPX + f) * 512 + node] = f32_bf16(tile[tx][ty + r * 8]);
    }
    const int nd = tid >> 3, sl = tid & 7;        // pad_x from same tile
    const int row = b * NN + kt * 32 + nd;
    f32x4 v; us4 o;
    #pragma unroll
    for (int t2 = 0; t2 < 4; ++t2) {
      const float x = tile[nd][sl * 4 + t2];
      v[t2] = x; o[t2] = f32_bf16(x);
    }
    Xpad[(size_t)row * F4 + ft * 8 + sl] = v;
    *(us4*)(Xcat + (size_t)row * KS1 + ft * 32 + sl * 4) = o;
  } else if (blk < 6400) {
    __shared__ float tile[32][33];
    const int bb = blk - 5120;                    // 40 kt x 32 nt
    const int kt = bb % 40, nt = bb / 40;
    const int tx = tid & 31, ty = tid >> 5;
    #pragma unroll
    for (int r = 0; r < 4; ++r) {
      int k = kt * 32 + ty + r * 8;
      int n = nt * 32 + tx;
      float v = 0.f;
      int c = -1, kk = 0;
      if (k < 625) { c = 0; kk = k; }
      else if (k >= 640 && k < 1265) { c = 1; kk = k - 640; }
      if (c >= 0 && n < FH) v = W1[((size_t)c * 625 + kk) * FH + n];
      tile[ty + r * 8][tx] = v;
    }
    __syncthreads();
    #pragma unroll
    for (int r = 0; r < 4; ++r) {
      int n = nt * 32 + ty + r * 8;
      int k = kt * 32 + tx;
      W1t[(size_t)n * KS1 + k] = f32_bf16(tile[tx][ty + r * 8]);
    }
  } else if (blk < 7600) {
    __shared__ float tile[32][33];
    const int bb = blk - 6400;                    // 60 kt x 20 nt
    const int kt = bb % 60, nt = bb / 60;
    const int tx = tid & 31, ty = tid >> 5;
    #pragma unroll
    for (int r = 0; r < 4; ++r) {
      int k = kt * 32 + ty + r * 8;
      int n = nt * 32 + tx;
      float v = 0.f;
      int c = -1, kk = 0;
      if (k < 937) { c = 0; kk = k; }
      else if (k >= 960 && k < 1897) { c = 1; kk = k - 960; }
      if (c >= 0 && n < FF) v = W2[((size_t)c * 937 + kk) * FF + n];
      tile[ty + r * 8][tx] = v;
    }
    __syncthreads();
    #pragma unroll
    for (int r = 0; r < 4; ++r) {
      int n = nt * 32 + ty + r * 8;
      int k = kt * 32 + tx;
      W2t[(size_t)n * KS2 + k] = f32_bf16(tile[tx][ty + r * 8]);
    }
  } else {
    __shared__ float sa[512];
    __shared__ u16 so[512];
    const int b = blk - 7600;
    // zero this batch's gmask (re-poisoned 0xAA every call)
    u32* gm = gmask + (size_t)b * 512 * 16;
    for (int s = tid; s < 512 * 16; s += 256) gm[s] = 0;
    sa[tid] = att[b * NN + tid]; sa[tid + 256] = att[b * NN + tid + 256];
    so[tid] = (u16)tid; so[tid + 256] = (u16)(tid + 256);
    for (int k = 2; k <= 512; k <<= 1) {
      for (int j = k >> 1; j > 0; j >>= 1) {
        __syncthreads();
        const int i = ((tid & ~(j - 1)) << 1) | (tid & (j - 1));
        const int p = i | j;
        const bool up = ((i & k) == 0);
        const float va = sa[i], vp = sa[p];
        if ((va > vp) == up) {
          sa[i] = vp; sa[p] = va;
          const u16 t = so[i]; so[i] = so[p]; so[p] = t;
        }
      }
    }
    __syncthreads();
    att_s[b * NN + tid] = sa[tid]; att_s[b * NN + tid + 256] = sa[tid + 256];
    ord_g[b * NN + tid] = so[tid]; ord_g[b * NN + tid + 256] = so[tid + 256];
  }
}

// ---------------------------------------------------------------------------
// build_L3: 4 att-sorted i-rows per block (LDS), SYMMETRIC upper-triangle:
// j-loop starts at s0+1; each accepted edge sets both rows' bits in global
// gmask (sorted space). One j per FULL wave: j is wave-uniform ->
// readfirstlane base -> SGPR addressing (kills per-lane 64-bit addr VALU that
// blew R9 to 84 VGPR / 24% occ). Packed 4-wide 6-step butterfly.
// ---------------------------------------------------------------------------
__global__ __launch_bounds__(256) void build_L3(
    const f32x4* __restrict__ Xpad,
    const float* __restrict__ att_s, const u16* __restrict__ ord_g,
    u32* __restrict__ gmask)
{
  __shared__ f32x4 Xi[ITILE][F4];   // 10 KB
  __shared__ float as_[512];        // 2 KB
  __shared__ u16 ord[512];          // 1 KB
  __shared__ int jhi_s;

  const int tid = threadIdx.x;
  const int blk = blockIdx.x;                  // 2048, XCD = blk&7
  const int xcd = blk & 7, sub = blk >> 3;     // sub 0..255
  const int b = xcd * 2 + (sub >> 7);
  const int s0 = (sub & 127) * ITILE;
  const f32x4* Xb4 = Xpad + (size_t)b * NN * F4;

  as_[tid] = att_s[b * NN + tid]; as_[tid + 256] = att_s[b * NN + tid + 256];
  ord[tid] = ord_g[b * NN + tid]; ord[tid + 256] = ord_g[b * NN + tid + 256];
  __syncthreads();

  for (int s = tid; s < ITILE * F4; s += 256) {
    const int ii = s / F4, k4 = s - ii * F4;
    Xi[ii][k4] = Xb4[(size_t)ord[s0 + ii] * F4 + k4];
  }
  if (tid == 0) {
    const float hit = as_[s0 + ITILE - 1] + 0.05f;
    int lo = 0, hi = 512;
    while (lo < hi) { int m = (lo + hi) >> 1; if (as_[m] <= hit) lo = m + 1; else hi = m; }
    jhi_s = lo;
  }
  __syncthreads();

  const int lane = tid & 63;
  const int wave = tid >> 6;
  const int jhi = jhi_s;
  const f32x4 zero = {0.f, 0.f, 0.f, 0.f};

  for (int sj = s0 + 1 + wave; sj < jhi; sj += 4) {
    const int oj = __builtin_amdgcn_readfirstlane((int)ord[sj]);
    const f32x4* Xj = Xb4 + (size_t)oj * F4;     // SGPR base + lane offset
    const f32x4 xj0 = Xj[lane];
    const f32x4 xj1 = Xj[64 + lane];
    const f32x4 xj2 = (lane < 32) ? Xj[128 + lane] : zero;
    const float aj = as_[sj];
    f32x4 pv;
    #pragma unroll
    for (int ii = 0; ii < ITILE; ++ii) {
      const f32x4 d0 = Xi[ii][lane] - xj0;
      const f32x4 d1 = Xi[ii][64 + lane] - xj1;
      const f32x4 d2 = (lane < 32) ? (Xi[ii][128 + lane] - xj2) : zero;
      float p = 0.f;
      #pragma unroll
      for (int t = 0; t < 4; ++t)
        p += fabsf(d0[t]) + fabsf(d1[t]) + fabsf(d2[t]);
      pv[ii] = p;
    }
    #pragma unroll
    for (int off = 32; off; off >>= 1) {          // packed full-wave butterfly
      f32x4 o;
      o[0] = __shfl_xor(pv[0], off, 64);
      o[1] = __shfl_xor(pv[1], off, 64);
      o[2] = __shfl_xor(pv[2], off, 64);
      o[3] = __shfl_xor(pv[3], off, 64);
      pv += o;
    }
    if (lane == 0) {
      #pragma unroll
      for (int ii = 0; ii < ITILE; ++ii) {
        const int si = s0 + ii;
        if (sj > si && fabsf(aj - as_[si]) <= 0.05f && pv[ii] <= 180.0f) {
          atomicOr(&gmask[((size_t)b * 512 + si) * 16 + (sj >> 5)], 1u << (sj & 31));
          atomicOr(&gmask[((size_t)b * 512 + sj) * 16 + (si >> 5)], 1u << (si & 31));
        }
      }
    }
  }
}

// ---------------------------------------------------------------------------
// write_L: gmask (sorted space) -> full coalesced L rows in original coords.
// deg = popcount(row mask); diagonal = self. 512 XCD-aligned blocks x 16 rows.
// ---------------------------------------------------------------------------
__global__ __launch_bounds__(256) void write_L(
    const u32* __restrict__ gmask, const u16* __restrict__ ord_g,
    u16* __restrict__ L)
{
  __shared__ u32 msk[16][16];
  __shared__ u16 ord[512];
  __shared__ u16 inv[512];
  __shared__ u16 dvs[16];

  const int tid = threadIdx.x;
  const int blk = blockIdx.x;                  // 512
  const int xcd = blk & 7, sub = blk >> 3;     // sub 0..63
  const int b = xcd * 2 + (sub >> 5);
  const int s0 = (sub & 31) * 16;

  const u16 o0 = ord_g[b * NN + tid], o1 = ord_g[b * NN + tid + 256];
  ord[tid] = o0; ord[tid + 256] = o1;
  inv[o0] = (u16)tid; inv[o1] = (u16)(tid + 256);
  if (tid < 256) msk[tid >> 4][tid & 15] =
      gmask[((size_t)b * 512 + s0 + (tid >> 4)) * 16 + (tid & 15)];
  __syncthreads();

  if (tid < 16) {
    int d = 0;
    #pragma unroll
    for (int w = 0; w < 16; ++w) d += __popc(msk[tid][w]);
    dvs[tid] = f32_bf16(1.0f / (float)(d + 1));
  }
  __syncthreads();

  #pragma unroll 4
  for (int ii = 0; ii < 16; ++ii) {
    const int oi = ord[s0 + ii];
    const u16 dv = dvs[ii];
    const int j0 = 2 * tid;
    const int sA = inv[j0], sB = inv[j0 + 1];
    const u32 fA = (j0 == oi)     | ((msk[ii][sA >> 5] >> (sA & 31)) & 1u);
    const u32 fB = (j0 + 1 == oi) | ((msk[ii][sB >> 5] >> (sB & 31)) & 1u);
    *(u32*)(L + ((size_t)b * 512 + oi) * 512 + j0) =
        (fA ? (u32)dv : 0u) | ((fB ? (u32)dv : 0u) << 16);
  }
}

// ---------------------------------------------------------------------------
// gemm_core: 128M x NTILE-N, BK=64, XOR chunk swizzle (R5-R7 proven).
// ---------------------------------------------------------------------------
template <int KS, int NTILE, int NREAL, int NSTORE, bool RELU, bool BIAS, bool OUT_BF16>
__device__ __forceinline__ void gemm_core(
    const u16* __restrict__ At, const u16* __restrict__ Btt,
    const float* __restrict__ bias, void* __restrict__ C,
    long crow0, int col0, int ldc)
{
  constexpr int NI = NTILE / 32;
  constexpr int BR = NTILE / 32;
  __shared__ __align__(16) u16 Ash[128 * 64];
  __shared__ __align__(16) u16 Bsh[NTILE * 64];

  const int tid  = threadIdx.x;
  const int lane = tid & 63;
  const int wave = tid >> 6;
  const int wm = wave & 1, wn = wave >> 1;
  const int q = lane >> 4, l16 = lane & 15;

  const u16* pa[4]; const u16* pb[BR];
  #pragma unroll
  for (int r = 0; r < 4; ++r) {
    const int ci = r * 256 + tid;
    const int row = ci >> 3, cpos = ci & 7;
    pa[r] = At + (size_t)row * KS + (cpos ^ (row & 7)) * 8;
  }
  #pragma unroll
  for (int r = 0; r < BR; ++r) {
    const int ci = r * 256 + tid;
    const int row = ci >> 3, cpos = ci & 7;
    pb[r] = Btt + (size_t)row * KS + (cpos ^ (row & 7)) * 8;
  }
  const int wbase = (tid & 192) * 8;

  const frag_ab* fA[4][2]; const frag_ab* fB[NI][2];
  #pragma unroll
  for (int mi = 0; mi < 4; ++mi) {
    const int row = wm * 64 + mi * 16 + l16;
    fA[mi][0] = (const frag_ab*)&Ash[row * 64 + ((q    ) ^ (l16 & 7)) * 8];
    fA[mi][1] = (const frag_ab*)&Ash[row * 64 + ((q + 4) ^ (l16 & 7)) * 8];
  }
  #pragma unroll
  for (int ni = 0; ni < NI; ++ni) {
    const int row = wn * (NTILE / 2) + ni * 16 + l16;
    fB[ni][0] = (const frag_ab*)&Bsh[row * 64 + ((q    ) ^ (l16 & 7)) * 8];
    fB[ni][1] = (const frag_ab*)&Bsh[row * 64 + ((q + 4) ^ (l16 & 7)) * 8];
  }

  frag_cd acc[4][NI] = {};

  constexpr int KT = KS / 64;
  for (int kt = 0; kt < KT; ++kt) {
    __syncthreads();
    #pragma unroll
    for (int r = 0; r < 4; ++r) { gload_lds16(pa[r], &Ash[r * 2048 + wbase]); pa[r] += 64; }
    #pragma unroll
    for (int r = 0; r < BR; ++r) { gload_lds16(pb[r], &Bsh[r * 2048 + wbase]); pb[r] += 64; }
    __syncthreads();

    #pragma unroll
    for (int kk = 0; kk < 2; ++kk) {
      frag_ab av[4], bv[NI];
      #pragma unroll
      for (int mi = 0; mi < 4; ++mi) av[mi] = *fA[mi][kk];
      #pragma unroll
      for (int ni = 0; ni < NI; ++ni) bv[ni] = *fB[ni][kk];
      #pragma unroll
      for (int mi = 0; mi < 4; ++mi)
        #pragma unroll
        for (int ni = 0; ni < NI; ++ni)
          acc[mi][ni] = __builtin_amdgcn_mfma_f32_16x16x32_bf16(
              av[mi], bv[ni], acc[mi][ni], 0, 0, 0);
    }
  }

  #pragma unroll
  for (int ni = 0; ni < NI; ++ni) {
    const int col = col0 + wn * (NTILE / 2) + ni * 16 + l16;
    if (col >= NSTORE) continue;
    const bool ok = (col < NREAL);
    float bvv = 0.f;
    if (BIAS) bvv = ok ? bias[col] : 0.f;
    #pragma unroll
    for (int mi = 0; mi < 4; ++mi) {
      #pragma unroll
      for (int r = 0; r < 4; ++r) {
        const long rowg = crow0 + wm * 64 + mi * 16 + q * 4 + r;
        float v = acc[mi][ni][r];
        if (BIAS) v += bvv;
        if (RELU) v = fmaxf(v, 0.f);
        if (!ok) v = 0.f;
        if (OUT_BF16) ((u16*)C)[rowg * (size_t)ldc + col] = f32_bf16(v);
        else          ((float*)C)[rowg * (size_t)ldc + col] = v;
      }
    }
  }
}

template <int KS, int NTILE, int NREAL, int NSTORE, bool RELU, bool BIAS, bool OUT_BF16>
__global__ __launch_bounds__(256) void gemm_dense(
    const u16* __restrict__ A, const u16* __restrict__ Bt,
    const float* __restrict__ bias, void* __restrict__ C, int ldc)
{
  const int x = blockIdx.x;
  const int mt = ((x & 7) << 3) | (x >> 3);      // XCD-aligned m-tile (R6)
  gemm_core<KS, NTILE, NREAL, NSTORE, RELU, BIAS, OUT_BF16>(
      A + (size_t)mt * 128 * KS, Bt + (size_t)blockIdx.y * NTILE * KS,
      bias, C, (long)mt * 128, blockIdx.y * NTILE, ldc);
}

// batched spmm: t = L_b · B_b^T; batch b on XCD b/2 (L2-local).
template <int NP>
__global__ __launch_bounds__(256) void spmm(
    const u16* __restrict__ L, const u16* __restrict__ Bt,
    u16* __restrict__ C, int ldc)
{
  constexpr int TPB = 4 * (NP / 64);
  const int blk = blockIdx.x;
  const int xcd = blk & 7, sub = blk >> 3;
  const int b = xcd * 2 + sub / TPB;
  const int t = sub % TPB;
  const int mt = t & 3, nt = t >> 2;
  gemm_core<512, 64, NP, NP, false, false, true>(
      L + ((size_t)b * 512 + mt * 128) * 512,
      Bt + ((size_t)b * NP + nt * 64) * 512,
      nullptr, C, (long)b * 512 + mt * 128, nt * 64, ldc);
}

// ---------------------------------------------------------------------------
// transpose_h (coalesced): hcat h-half -> ht [b][960][512] bf16.
// ---------------------------------------------------------------------------
__global__ __launch_bounds__(256) void transpose_h(
    const u16* __restrict__ hcat, u16* __restrict__ ht)
{
  __shared__ u16 tile[32][34];
  const int blk = blockIdx.x;                   // 7680
  const int xcd = blk & 7, sub = blk >> 3;      // sub 0..959
  const int b = xcd * 2 + sub / 480;
  const int t = sub % 480;
  const int kt = t % 16, nt = t / 16;
  const int tid = threadIdx.x;
  const int tx = tid & 31, ty = tid >> 5;
  #pragma unroll
  for (int r = 0; r < 4; ++r) {
    const int node = kt * 32 + ty + r * 8;
    const int n = nt * 32 + tx;
    tile[ty + r * 8][tx] = hcat[((size_t)b * NN + node) * KS2 + n];
  }
  __syncthreads();
  #pragma unroll
  for (int r = 0; r < 4; ++r) {
    const int n = nt * 32 + ty + r * 8;
    const int node = kt * 32 + tx;
    ht[((size_t)b * NPH + n) * 512 + node] = tile[tx][ty + r * 8];
  }
}

// ---------------------------------------------------------------------------
extern "C" void kernel_launch(void* const* d_in, const int* in_sizes, int n_in,
                              void* d_out, int out_size, void* d_ws, size_t ws_size,
                              hipStream_t stream) {
  const float* x4  = (const float*)d_in[0];
  const float* att = (const float*)d_in[1];
  const float* W1  = (const float*)d_in[2];
  const float* b1  = (const float*)d_in[3];
  const float* W2  = (const float*)d_in[4];
  const float* b2  = (const float*)d_in[5];
  float* out = (float*)d_out;

  char* ws = (char*)d_ws;
  f32x4* Xpad = (f32x4*)ws;                                 // 20.97 MB
  u16* ht = (u16*)ws;       ws += (size_t)ROWS * F4 * 16;   // ht aliases Xpad
                                                            // (dead after build_L3)
  u16* Xcat = (u16*)ws;  ws += (size_t)ROWS * KS1 * 2;      // 20.97 MB
  u16* hcat = (u16*)ws;  ws += (size_t)ROWS * KS2 * 2;      // 31.46 MB
  u16* W1t  = (u16*)ws;  ws += (size_t)1024 * KS1 * 2;      //  2.62 MB
  u16* W2t  = (u16*)ws;  ws += (size_t)640 * KS2 * 2;       //  2.46 MB
  u16* Lm   = (u16*)ws;  ws += (size_t)NB * 512 * 512 * 2;  //  8.39 MB
  u16* Xt   = (u16*)ws;  ws += (size_t)NB * NPX * 512 * 2;  // 10.49 MB
  u32* gmask = (u32*)ws; ws += (size_t)ROWS * 16 * 4;       // 512 KB
  float* att_s = (float*)ws; ws += (size_t)NB * NN * 4;     // 32 KB
  u16* ord_g   = (u16*)ws;   ws += (size_t)NB * NN * 2;     // 16 KB

  prep<<<dim3(7616), 256, 0, stream>>>(x4, att, W1, W2, Xpad, Xcat, Xt,
                                       W1t, W2t, att_s, ord_g, gmask);
  build_L3<<<dim3(2048), 256, 0, stream>>>(Xpad, att_s, ord_g, gmask);
  write_L<<<dim3(512), 256, 0, stream>>>(gmask, ord_g, Lm);
  spmm<NPX><<<dim3(640), 256, 0, stream>>>(Lm, Xt, Xcat + NPX, KS1);
  gemm_dense<KS1, 128, FH, NPH, true, true, true>
      <<<dim3(64, 8), 256, 0, stream>>>(Xcat, W1t, b1, (void*)hcat, KS2);
  transpose_h<<<dim3(7680), 256, 0, stream>>>(hcat, ht);
  spmm<NPH><<<dim3(960), 256, 0, stream>>>(Lm, ht, hcat + NPH, KS2);
  gemm_dense<KS2, 64, FF, FF, true, true, false>
      <<<dim3(64, 10), 256, 0, stream>>>(hcat, W2t, b2, (void*)out, FF);
}